// Round 8
// baseline (450.689 us; speedup 1.0000x reference)
//
#include <hip/hip_runtime.h>
#include <math.h>

#define N_ROWS 16384
#define DMODEL 1024
#define DFF    4096

typedef _Float16 f16;
typedef __attribute__((ext_vector_type(4))) _Float16 f16x4;
typedef __attribute__((ext_vector_type(8))) _Float16 f16x8;
typedef __attribute__((ext_vector_type(4))) float f32x4;

__device__ inline void async_ld16(const f16* g, f16* l) {
  __builtin_amdgcn_global_load_lds(
      (__attribute__((address_space(1))) void*)(g),
      (__attribute__((address_space(3))) void*)(l),
      16, 0, 0);
}

// tanh via hw v_exp_f32: ~5 VALU ops vs libm tanhf's branchy ~40.
__device__ inline float fast_tanh(float x) {
  float t = __expf(2.0f * x);
  return 1.0f - 2.0f / (t + 1.0f);
}

__global__ void cast_to_f16(const float* __restrict__ src, f16* __restrict__ dst, int n) {
  int i = (blockIdx.x * blockDim.x + threadIdx.x) * 8;
  if (i >= n) return;
  float4 v0 = ((const float4*)(src + i))[0];
  float4 v1 = ((const float4*)(src + i))[1];
  f16x8 h = { (f16)v0.x, (f16)v0.y, (f16)v0.z, (f16)v0.w,
              (f16)v1.x, (f16)v1.y, (f16)v1.z, (f16)v1.w };
  *(f16x8*)(dst + i) = h;
}

#define BARRIER() __builtin_amdgcn_s_barrier()
#define WAIT_VMCNT(n) asm volatile("s_waitcnt vmcnt(" #n ")")
#define WAIT_LGKM(n)  asm volatile("s_waitcnt lgkmcnt(" #n ")")

// ---------------------------------------------------------------------------
// FAITHFUL m201 PORT (r7 post-mortem: six self-designed schedules all pinned
// at 790 TF / 35%; this is the verified-1563TF template, element by element).
//
// C[M,Nc] = tanh(A[M,K] @ B[Nc,K]^T + bias), f16, fp32 acc.
// 256x256 tile, BK=64, 512 thr, 8 waves 2Mx4N (per-wave 128x64).
//
// LDS 128KB = 2 dbuf x {Ah0,Ah1,Bh0,Bh1} x 16KB. Half-tile = 128 rows x 64 k,
// row-major, 128B rows, st_16x32 swizzle: byte ^= ((byte>>9)&1)<<5
// i.e. 16B-slot ^= ((row>>2)&1)<<1. Both-sides: DMA dest linear, global
// source slot pre-XORed with the same involution; reads XOR on the fly.
// Residual ~4-way bank aliasing is EXPECTED (m201 ships with it; 267K conflicts
// measured at 62% util) - do not "fix" back to the 64B-row layout.
//
// Per K-tile, 4 phases, each = {ds_reads, stage, bar, lgkm(0), setprio1,
// 16 MFMA (one C-quadrant x K=64), setprio0, bar}:
//   P0: read b01[2kk](4) + a03[2kk](8) | stage Ah1(t+1)->d^1 | Q(m0-3,n0-1)
//   P1: read a47[2kk](8)               |                     | Q(m4-7,n0-1)
//   P2: read b23[2kk](4)               |                     | Q(m0-3,n2-3)
//   P3: (no reads) | stage Bh0,Bh1,Ah0(t+2)->d | Q(m4-7,n2-3) | vmcnt(6) | bar
// Stage-issue safety is BARRIER-anchored: Ah1(t+1) region's last reader was
// tile t-1 P1 (>=2 barriers back); Bh*(t+2) after P2-close (B reads end P2);
// Ah0(t+2) after P2-close (A reads end P1).
// vmcnt ledger (in-order retirement): at P3 wait, queue = [Bh0,Bh1,Ah0(t+1)
// @P3(t-1); Ah1(t+1)@P0(t); Bh0,Bh1,Ah0(t+2)@P3(t)] = 14 loads; vmcnt(6)
// retires 8 = ALL of tile t+1, leaves t+2's six in flight. Never drains to 0
// except the two tail tiles. Prologue: t0 (4 halves) + t1 (3 halves),
// vmcnt(6) retires exactly t0.
// ---------------------------------------------------------------------------
template <int K>
__global__ __launch_bounds__(512, 2)
void gemm256_tanh(const f16* __restrict__ A, const f16* __restrict__ B,
                  const float* __restrict__ bias, f16* __restrict__ C, int Nc) {
  extern __shared__ __align__(16) char smem[];
  f16* lds = (f16*)smem;

  const int tid  = threadIdx.x;
  const int lane = tid & 63;
  const int wave = tid >> 6;
  const int wm = (wave >> 2) * 128;
  const int wn = (wave & 3) * 64;
  const int fr = lane & 15;
  const int g  = lane >> 4;

  // T1: XCD-aware swizzle (nwg % 8 == 0 for both GEMMs here)
  const int nbx = gridDim.x;
  const int nwg = nbx * gridDim.y;
  const int lin = blockIdx.y * nbx + blockIdx.x;
  const int swz = (lin & 7) * (nwg >> 3) + (lin >> 3);
  const size_t row0 = (size_t)(swz % nbx) * 256;
  const size_t col0 = (size_t)(swz / nbx) * 256;

  // Staging: half-tile (128x64) = 512 thr x 2 x 16B. Thread slot q covers
  // row = q*64 + (tid>>3), 16B-slot (tid&7). Source slot pre-swizzled:
  // (row>>2)&1 == (tid>>5)&1 for both q.
  const int srow  = tid >> 3;
  const int sslot = (tid & 7) ^ (((tid >> 5) & 1) << 1);
  auto stage_half = [&](int op, int h, int db, int kb) {
    const f16* src = (op ? B : A);
    const size_t base = (op ? col0 : row0);
#pragma unroll
    for (int q = 0; q < 2; ++q) {
      const f16* gp = src + (base + h * 128 + q * 64 + srow) * (size_t)K + kb + sslot * 8;
      f16* lp = lds + db * 32768 + op * 16384 + h * 8192 + q * 4096 + tid * 8;
      async_ld16(gp, lp);
    }
  };

  // Fragment reads: row-local swizzle bit ((row>>2)&1) == (fr>>2)&1 for all
  // m,n (m*16, wn, wm are multiples of 8 rows).
  const int xr  = ((fr >> 2) & 1) << 1;
  const int hA  = wm >> 7;
  const int hB  = wn >> 7;
  const int wnl = wn & 127;
  auto aoff = [&](int d, int m, int kk) -> int {
    return d * 32768 + hA * 8192 + (m * 16 + fr) * 64 + (((kk * 4 + g) ^ xr) * 8);
  };
  auto boff = [&](int d, int n, int kk) -> int {
    return d * 32768 + 16384 + hB * 8192 + (wnl + n * 16 + fr) * 64 + (((kk * 4 + g) ^ xr) * 8);
  };

  f32x4 acc[8][4] = {};
  constexpr int NT = K / 64;

  // Prologue: tile0 all 4 halves, tile1 three halves (Ah1(t1) issues at P0(t0))
  stage_half(1, 0, 0, 0);  stage_half(1, 1, 0, 0);
  stage_half(0, 0, 0, 0);  stage_half(0, 1, 0, 0);
  stage_half(1, 0, 1, 64); stage_half(1, 1, 1, 64);
  stage_half(0, 0, 1, 64);
  WAIT_VMCNT(6);   // retires tile0's 8 loads exactly
  BARRIER();

  for (int t = 0; t < NT; ++t) {
    const int d = t & 1;
    const bool pre1 = (t + 1) < NT;
    const bool pre2 = (t + 2) < NT;

    f16x8 alo[4][2], ahi[4][2], blo[2][2], bhi[2][2];

    // ---- P0: b01 + a03 | stage Ah1(t+1) | Q(m0-3, n0-1) ----
#pragma unroll
    for (int n = 0; n < 2; ++n)
#pragma unroll
      for (int kk = 0; kk < 2; ++kk) blo[n][kk] = *(const f16x8*)(lds + boff(d, n, kk));
#pragma unroll
    for (int m = 0; m < 4; ++m)
#pragma unroll
      for (int kk = 0; kk < 2; ++kk) alo[m][kk] = *(const f16x8*)(lds + aoff(d, m, kk));
    if (pre1) stage_half(0, 1, d ^ 1, (t + 1) * 64);
    WAIT_LGKM(8);   // 12 reads this phase: start service before barrier
    BARRIER();
    WAIT_LGKM(0);
    __builtin_amdgcn_s_setprio(1);
#pragma unroll
    for (int kk = 0; kk < 2; ++kk)
#pragma unroll
      for (int m = 0; m < 4; ++m)
#pragma unroll
        for (int n = 0; n < 2; ++n)
          acc[m][n] = __builtin_amdgcn_mfma_f32_16x16x32_f16(alo[m][kk], blo[n][kk], acc[m][n], 0, 0, 0);
    __builtin_amdgcn_s_setprio(0);
    BARRIER();

    // ---- P1: a47 | Q(m4-7, n0-1) ----
#pragma unroll
    for (int m = 0; m < 4; ++m)
#pragma unroll
      for (int kk = 0; kk < 2; ++kk) ahi[m][kk] = *(const f16x8*)(lds + aoff(d, 4 + m, kk));
    BARRIER();
    WAIT_LGKM(0);
    __builtin_amdgcn_s_setprio(1);
#pragma unroll
    for (int kk = 0; kk < 2; ++kk)
#pragma unroll
      for (int m = 0; m < 4; ++m)
#pragma unroll
        for (int n = 0; n < 2; ++n)
          acc[4 + m][n] = __builtin_amdgcn_mfma_f32_16x16x32_f16(ahi[m][kk], blo[n][kk], acc[4 + m][n], 0, 0, 0);
    __builtin_amdgcn_s_setprio(0);
    BARRIER();

    // ---- P2: b23 | Q(m0-3, n2-3) ----
#pragma unroll
    for (int n = 0; n < 2; ++n)
#pragma unroll
      for (int kk = 0; kk < 2; ++kk) bhi[n][kk] = *(const f16x8*)(lds + boff(d, 2 + n, kk));
    BARRIER();
    WAIT_LGKM(0);
    __builtin_amdgcn_s_setprio(1);
#pragma unroll
    for (int kk = 0; kk < 2; ++kk)
#pragma unroll
      for (int m = 0; m < 4; ++m)
#pragma unroll
        for (int n = 0; n < 2; ++n)
          acc[m][2 + n] = __builtin_amdgcn_mfma_f32_16x16x32_f16(alo[m][kk], bhi[n][kk], acc[m][2 + n], 0, 0, 0);
    __builtin_amdgcn_s_setprio(0);
    BARRIER();

    // ---- P3: stage Bh0,Bh1,Ah0(t+2)->d | Q(m4-7, n2-3) | vmcnt(6) ----
    if (pre2) {
      const int kb2 = (t + 2) * 64;
      stage_half(1, 0, d, kb2);
      stage_half(1, 1, d, kb2);
      stage_half(0, 0, d, kb2);
    }
    BARRIER();
    __builtin_amdgcn_s_setprio(1);
#pragma unroll
    for (int kk = 0; kk < 2; ++kk)
#pragma unroll
      for (int m = 0; m < 4; ++m)
#pragma unroll
        for (int n = 0; n < 2; ++n)
          acc[4 + m][2 + n] = __builtin_amdgcn_mfma_f32_16x16x32_f16(ahi[m][kk], bhi[n][kk], acc[4 + m][2 + n], 0, 0, 0);
    __builtin_amdgcn_s_setprio(0);
    if (pre2)      { WAIT_VMCNT(6); }  // tile t+1 fully landed; t+2's 3 halves in flight
    else           { WAIT_VMCNT(0); }  // tails: drain
    BARRIER();
  }

  // Epilogue; C/D map: col=lane&15, row=(lane>>4)*4+reg [m89-verified]
#pragma unroll
  for (int m = 0; m < 8; ++m) {
#pragma unroll
    for (int n = 0; n < 4; ++n) {
      const size_t gcol = col0 + wn + n * 16 + fr;
      const float bia = bias[gcol];
      f16* Cp = C + (row0 + wm + m * 16 + g * 4) * (size_t)Nc + gcol;
#pragma unroll
      for (int r = 0; r < 4; ++r)
        Cp[(size_t)r * Nc] = (f16)fast_tanh(acc[m][n][r] + bia);
    }
  }
}

// out[row] = sigmoid(sum_k wx[row][k] * batch[row][k]); 256 thr/row, fp32 acc
__global__ void rowdot_sigmoid(const f16* __restrict__ wx, const float* __restrict__ batch,
                               float* __restrict__ out) {
  const int row = blockIdx.x;
  const int t = threadIdx.x;
  const f16* wr = wx + (size_t)row * DMODEL + t * 4;
  const float* br = batch + (size_t)row * DMODEL + t * 4;
  f16x4 h = *(const f16x4*)wr;
  float4 b4 = *(const float4*)br;
  float s = (float)h[0] * b4.x + (float)h[1] * b4.y + (float)h[2] * b4.z + (float)h[3] * b4.w;
#pragma unroll
  for (int off = 32; off > 0; off >>= 1) s += __shfl_down(s, off, 64);
  __shared__ float partial[4];
  if ((t & 63) == 0) partial[t >> 6] = s;
  __syncthreads();
  if (t == 0) {
    float tot = partial[0] + partial[1] + partial[2] + partial[3];
    out[row] = 1.0f / (1.0f + __expf(-tot));
  }
}

extern "C" void kernel_launch(void* const* d_in, const int* in_sizes, int n_in,
                              void* d_out, int out_size, void* d_ws, size_t ws_size,
                              hipStream_t stream) {
  const float* batch = (const float*)d_in[0];
  const float* W1    = (const float*)d_in[1];
  const float* b1    = (const float*)d_in[2];
  const float* W2    = (const float*)d_in[3];
  const float* b2    = (const float*)d_in[4];
  float* out = (float*)d_out;

  char* ws = (char*)d_ws;
  f16* batch_h = (f16*)ws;  ws += (size_t)N_ROWS * DMODEL * sizeof(f16);  //  32 MB
  f16* W1_h    = (f16*)ws;  ws += (size_t)DFF * DMODEL * sizeof(f16);     //   8 MB
  f16* W2_h    = (f16*)ws;  ws += (size_t)DMODEL * DFF * sizeof(f16);     //   8 MB
  f16* inner_h = (f16*)ws;  ws += (size_t)N_ROWS * DFF * sizeof(f16);     // 128 MB
  f16* wx_h    = (f16*)ws;  ws += (size_t)N_ROWS * DMODEL * sizeof(f16);  //  32 MB

  static bool attr_set = false;
  if (!attr_set) {
    (void)hipFuncSetAttribute((const void*)gemm256_tanh<DMODEL>,
                              hipFuncAttributeMaxDynamicSharedMemorySize, 131072);
    (void)hipFuncSetAttribute((const void*)gemm256_tanh<DFF>,
                              hipFuncAttributeMaxDynamicSharedMemorySize, 131072);
    attr_set = true;
  }

  const int nb = N_ROWS * DMODEL;
  const int nw = DFF * DMODEL;
  cast_to_f16<<<nb / 2048, 256, 0, stream>>>(batch, batch_h, nb);
  cast_to_f16<<<nw / 2048, 256, 0, stream>>>(W1, W1_h, nw);
  cast_to_f16<<<nw / 2048, 256, 0, stream>>>(W2, W2_h, nw);

  dim3 g1(N_ROWS / 256, DFF / 256);     // (64, 16)
  gemm256_tanh<DMODEL><<<g1, 512, 131072, stream>>>(batch_h, W1_h, b1, inner_h, DFF);
  dim3 g2(N_ROWS / 256, DMODEL / 256);  // (64, 4)
  gemm256_tanh<DFF><<<g2, 512, 131072, stream>>>(inner_h, W2_h, b2, wx_h, DMODEL);

  rowdot_sigmoid<<<N_ROWS, 256, 0, stream>>>(wx_h, batch, out);
}

// Round 9
// 434.912 us; speedup vs baseline: 1.0363x; 1.0363x over previous
//
#include <hip/hip_runtime.h>
#include <math.h>

#define N_ROWS 16384
#define DMODEL 1024
#define DFF    4096

typedef _Float16 f16;
typedef __attribute__((ext_vector_type(4))) _Float16 f16x4;
typedef __attribute__((ext_vector_type(8))) _Float16 f16x8;
typedef __attribute__((ext_vector_type(4))) float f32x4;

__device__ inline void async_ld16(const f16* g, f16* l) {
  __builtin_amdgcn_global_load_lds(
      (__attribute__((address_space(1))) void*)(g),
      (__attribute__((address_space(3))) void*)(l),
      16, 0, 0);
}

// tanh via hw v_exp_f32: ~5 VALU ops vs libm tanhf's branchy ~40.
__device__ inline float fast_tanh(float x) {
  float t = __expf(2.0f * x);
  return 1.0f - 2.0f / (t + 1.0f);
}

// Merged pre-pass: casts batch/W1/W2 f32->f16 AND zeroes the row-accumulator
// (no hipMemsetAsync needed). One launch instead of three + memset.
__global__ void cast_and_zero(const float* __restrict__ batch, f16* __restrict__ batch_h,
                              const float* __restrict__ W1, f16* __restrict__ W1_h,
                              const float* __restrict__ W2, f16* __restrict__ W2_h,
                              float* __restrict__ rowacc) {
  const size_t nb = (size_t)N_ROWS * DMODEL;
  const size_t nw = (size_t)DFF * DMODEL;
  size_t off = ((size_t)blockIdx.x * blockDim.x + threadIdx.x) * 8;
  const float* src; f16* dst; size_t o;
  if (off < nb) { src = batch; dst = batch_h; o = off; }
  else if (off < nb + nw) { src = W1; dst = W1_h; o = off - nb; }
  else if (off < nb + 2 * nw) { src = W2; dst = W2_h; o = off - nb - nw; }
  else {  // zero 8 floats of rowacc
    size_t z = off - nb - 2 * nw;
    float4 zz = {0.f, 0.f, 0.f, 0.f};
    ((float4*)(rowacc + z))[0] = zz;
    ((float4*)(rowacc + z))[1] = zz;
    return;
  }
  float4 v0 = ((const float4*)(src + o))[0];
  float4 v1 = ((const float4*)(src + o))[1];
  f16x8 h = { (f16)v0.x, (f16)v0.y, (f16)v0.z, (f16)v0.w,
              (f16)v1.x, (f16)v1.y, (f16)v1.z, (f16)v1.w };
  *(f16x8*)(dst + o) = h;
}

#define BARRIER() __builtin_amdgcn_s_barrier()
#define WAIT_VMCNT(n) asm volatile("s_waitcnt vmcnt(" #n ")")

// ---------------------------------------------------------------------------
// GEMM core = r6 structure (2-phase counted-vmcnt, 0 bank conflicts, best
// measured family member ~173us). r8 post-mortem: 7 schedule variants pin at
// 790+-5 TF; r0's 4.3GB staging in the same time proved memory delivery is
// not the pacer; schedule micro-structure closed. This round harvests fusion.
//
// FUSE=false: C[M,Nc] = tanh(A@B^T + bias) -> f16 (GEMM1).
// FUSE=true : no C write; per-row atomicAdd of
//             sum_col tanh(acc+bias)*batchf[row][col] into rowacc (GEMM2 +
//             rowdot fused; wx never materialized).
// ---------------------------------------------------------------------------
template <int K, bool FUSE>
__global__ __launch_bounds__(512, 2)
void gemm256_tanh(const f16* __restrict__ A, const f16* __restrict__ B,
                  const float* __restrict__ bias, f16* __restrict__ C, int Nc,
                  float* __restrict__ rowacc, const float* __restrict__ batchf) {
  extern __shared__ __align__(16) char smem[];
  f16* lds = (f16*)smem;

  const int tid  = threadIdx.x;
  const int lane = tid & 63;
  const int wave = tid >> 6;
  const int wm = (wave >> 2) * 128;
  const int wn = (wave & 3) * 64;
  const int fr = lane & 15;
  const int g  = lane >> 4;

  // T1: XCD-aware swizzle (nwg % 8 == 0 for both GEMMs here)
  const int nbx = gridDim.x;
  const int nwg = nbx * gridDim.y;
  const int lin = blockIdx.y * nbx + blockIdx.x;
  const int swz = (lin & 7) * (nwg >> 3) + (lin >> 3);
  const size_t row0 = (size_t)(swz % nbx) * 256;
  const size_t col0 = (size_t)(swz / nbx) * 256;

  // Staging: per unit (kk-half of one operand, 256x32 f16 = 16KB), thread
  // covers 16B slots s = l*512+tid; source chunk pre-swizzled (rule #21):
  // schunk = (s&3) ^ ((s>>3)&3).
  const int schunk = (tid & 3) ^ ((tid >> 3) & 3);
  const f16* Asrc[2]; const f16* Bsrc[2];
  const int sdst0 = tid * 8;
  const int sdst1 = 4096 + tid * 8;
  Asrc[0] = A + (row0 + (tid >> 2)) * (size_t)K + schunk * 8;
  Asrc[1] = A + (row0 + 128 + (tid >> 2)) * (size_t)K + schunk * 8;
  Bsrc[0] = B + (col0 + (tid >> 2)) * (size_t)K + schunk * 8;
  Bsrc[1] = B + (col0 + 128 + (tid >> 2)) * (size_t)K + schunk * 8;

  // LDS f16-offset helpers; read swizzle: slot ^= row bits 1-2 (conflict-free,
  // SQ_LDS_BANK_CONFLICT == 0 measured r3-r7).
  auto aoff = [&](int d, int kk, int m) -> int {
    const int row = wm + m * 16 + fr;
    return d * 32768 + kk * 8192 + row * 32 + (g ^ ((row >> 1) & 3)) * 8;
  };
  auto boff = [&](int d, int kk, int n) -> int {
    const int row = wn + n * 16 + fr;
    return d * 32768 + 16384 + kk * 8192 + row * 32 + (g ^ ((row >> 1) & 3)) * 8;
  };
  auto stage_unit = [&](int j, int db, int kb) {
    const int o = j & 1, kk = j >> 1;
    const int dbase = db * 32768 + o * 16384 + kk * 8192;
    async_ld16((o ? Bsrc[0] : Asrc[0]) + kb + kk * 32, lds + dbase + sdst0);
    async_ld16((o ? Bsrc[1] : Asrc[1]) + kb + kk * 32, lds + dbase + sdst1);
  };

  f32x4 acc[8][4] = {};
  constexpr int NT = K / 64;

  // Prologue: stage tile 0 (units 0..3) into dbuf 0; wait units 0,1.
  stage_unit(0, 0, 0);
  stage_unit(1, 0, 0);
  stage_unit(2, 0, 0);
  stage_unit(3, 0, 0);
  WAIT_VMCNT(4);
  BARRIER();

  for (int t = 0; t < NT; ++t) {
    const int d = t & 1;
    const bool pre = (t + 1) < NT;
    const int kpre = (t + 1) * 64;

    // ---- Phase A: kk0, 32 MFMA ----
    {
      f16x8 bfr[4], afr[8];
#pragma unroll
      for (int n = 0; n < 4; ++n) bfr[n] = *(const f16x8*)(lds + boff(d, 0, n));
#pragma unroll
      for (int i = 0; i < 8; ++i) afr[i] = *(const f16x8*)(lds + aoff(d, 0, i));
      if (pre) { stage_unit(0, d ^ 1, kpre); stage_unit(1, d ^ 1, kpre); }
      BARRIER();
      __builtin_amdgcn_s_setprio(1);
#pragma unroll
      for (int i = 0; i < 8; ++i)
#pragma unroll
        for (int n = 0; n < 4; ++n)
          acc[i][n] = __builtin_amdgcn_mfma_f32_16x16x32_f16(afr[i], bfr[n], acc[i][n], 0, 0, 0);
      __builtin_amdgcn_s_setprio(0);
      if (pre) { WAIT_VMCNT(4); }   // u2,u3(t) landed (in-order retirement)
      else     { WAIT_VMCNT(0); }   // tail drain
      BARRIER();
    }
    // ---- Phase B: kk1, 32 MFMA ----
    {
      f16x8 bfr[4], afr[8];
#pragma unroll
      for (int n = 0; n < 4; ++n) bfr[n] = *(const f16x8*)(lds + boff(d, 1, n));
#pragma unroll
      for (int i = 0; i < 8; ++i) afr[i] = *(const f16x8*)(lds + aoff(d, 1, i));
      if (pre) { stage_unit(2, d ^ 1, kpre); stage_unit(3, d ^ 1, kpre); }
      BARRIER();
      __builtin_amdgcn_s_setprio(1);
#pragma unroll
      for (int i = 0; i < 8; ++i)
#pragma unroll
        for (int n = 0; n < 4; ++n)
          acc[i][n] = __builtin_amdgcn_mfma_f32_16x16x32_f16(afr[i], bfr[n], acc[i][n], 0, 0, 0);
      __builtin_amdgcn_s_setprio(0);
      if (pre) { WAIT_VMCNT(4); }   // u0,u1(t+1) landed
      BARRIER();
    }
  }

  // Epilogue; C/D map: col=lane&15, row=(lane>>4)*4+reg [m89-verified]
  if constexpr (!FUSE) {
#pragma unroll
    for (int m = 0; m < 8; ++m) {
#pragma unroll
      for (int n = 0; n < 4; ++n) {
        const size_t gcol = col0 + wn + n * 16 + fr;
        const float bia = bias[gcol];
        f16* Cp = C + (row0 + wm + m * 16 + g * 4) * (size_t)Nc + gcol;
#pragma unroll
        for (int r = 0; r < 4; ++r)
          Cp[(size_t)r * Nc] = (f16)fast_tanh(acc[m][n][r] + bia);
      }
    }
  } else {
    // Fused rowdot: rsum[m][r] = sum_n tanh(acc+b)*batchf[row][col]; lane
    // covers cols wn+n*16+fr, rows wm+m*16+g*4+r. Reduce over fr (16 lanes,
    // shfl_xor 1/2/4/8 stays within the g-group), then 1 atomicAdd per row.
    float rsum[8][4];
#pragma unroll
    for (int m = 0; m < 8; ++m)
#pragma unroll
      for (int r = 0; r < 4; ++r) rsum[m][r] = 0.f;
#pragma unroll
    for (int m = 0; m < 8; ++m) {
#pragma unroll
      for (int n = 0; n < 4; ++n) {
        const size_t gcol = col0 + wn + n * 16 + fr;
        const float bia = bias[gcol];
        const float* bp = batchf + (row0 + wm + m * 16 + g * 4) * DMODEL + gcol;
#pragma unroll
        for (int r = 0; r < 4; ++r)
          rsum[m][r] += fast_tanh(acc[m][n][r] + bia) * bp[(size_t)r * DMODEL];
      }
    }
#pragma unroll
    for (int m = 0; m < 8; ++m) {
#pragma unroll
      for (int r = 0; r < 4; ++r) {
        float s = rsum[m][r];
        s += __shfl_xor(s, 1, 64);
        s += __shfl_xor(s, 2, 64);
        s += __shfl_xor(s, 4, 64);
        s += __shfl_xor(s, 8, 64);
        if (fr == 0)
          atomicAdd(&rowacc[row0 + wm + m * 16 + g * 4 + r], s);
      }
    }
  }
}

// out[row] = sigmoid(rowacc[row])
__global__ void sigmoid_rows(const float* __restrict__ rowacc, float* __restrict__ out) {
  const int i = blockIdx.x * blockDim.x + threadIdx.x;
  out[i] = 1.0f / (1.0f + __expf(-rowacc[i]));
}

extern "C" void kernel_launch(void* const* d_in, const int* in_sizes, int n_in,
                              void* d_out, int out_size, void* d_ws, size_t ws_size,
                              hipStream_t stream) {
  const float* batch = (const float*)d_in[0];
  const float* W1    = (const float*)d_in[1];
  const float* b1    = (const float*)d_in[2];
  const float* W2    = (const float*)d_in[3];
  const float* b2    = (const float*)d_in[4];
  float* out = (float*)d_out;

  char* ws = (char*)d_ws;
  f16* batch_h  = (f16*)ws;   ws += (size_t)N_ROWS * DMODEL * sizeof(f16);  //  32 MB
  f16* W1_h     = (f16*)ws;   ws += (size_t)DFF * DMODEL * sizeof(f16);     //   8 MB
  f16* W2_h     = (f16*)ws;   ws += (size_t)DMODEL * DFF * sizeof(f16);     //   8 MB
  f16* inner_h  = (f16*)ws;   ws += (size_t)N_ROWS * DFF * sizeof(f16);     // 128 MB
  float* rowacc = (float*)ws; ws += (size_t)N_ROWS * sizeof(float);         //  64 KB

  static bool attr_set = false;
  if (!attr_set) {
    (void)hipFuncSetAttribute((const void*)gemm256_tanh<DMODEL, false>,
                              hipFuncAttributeMaxDynamicSharedMemorySize, 131072);
    (void)hipFuncSetAttribute((const void*)gemm256_tanh<DFF, true>,
                              hipFuncAttributeMaxDynamicSharedMemorySize, 131072);
    attr_set = true;
  }

  // merged casts + rowacc zero: (nb + 2*nw)/8 + N_ROWS/8 threads
  const size_t nb = (size_t)N_ROWS * DMODEL;
  const size_t nw = (size_t)DFF * DMODEL;
  const int total_thr = (int)((nb + 2 * nw) / 8 + N_ROWS / 8);  // 3147776
  cast_and_zero<<<total_thr / 256, 256, 0, stream>>>(batch, batch_h, W1, W1_h,
                                                     W2, W2_h, rowacc);

  dim3 g1(N_ROWS / 256, DFF / 256);     // (64, 16)
  gemm256_tanh<DMODEL, false><<<g1, 512, 131072, stream>>>(
      batch_h, W1_h, b1, inner_h, DFF, nullptr, nullptr);
  dim3 g2(N_ROWS / 256, DMODEL / 256);  // (64, 4)
  gemm256_tanh<DFF, true><<<g2, 512, 131072, stream>>>(
      inner_h, W2_h, b2, nullptr, DMODEL, rowacc, batch);

  sigmoid_rows<<<N_ROWS / 256, 256, 0, stream>>>(rowacc, out);
}